// Round 8
// baseline (433.158 us; speedup 1.0000x reference)
//
#include <hip/hip_runtime.h>

typedef __bf16 bf16_t;
typedef __bf16 bf16x8 __attribute__((ext_vector_type(8)));
typedef __bf16 bf16x2 __attribute__((ext_vector_type(2)));
typedef float  f32x4  __attribute__((ext_vector_type(4)));

#define MFMA16(a,b,c) __builtin_amdgcn_mfma_f32_16x16x32_bf16((a),(b),(c),0,0,0)

// ---- constants (problem is fixed-shape) ----
#define BB 8
#define NN 2048
#define CC 128
#define CIN 64
#define KNB 16            // neighbors
#define BNT (BB*NN)       // 16384 points

// XCD affinity remaps: batch a block touches == blockIdx%8 == its XCD.
static __device__ __forceinline__ int remap256(int x) { return ((x & 7) << 5) | (x >> 3); }
static __device__ __forceinline__ int remap128(int x) { return ((x & 7) << 4) | (x >> 3); }

static __device__ __forceinline__ bf16x8 cvt8(const float* src) {
  f32x4 a0 = *(const f32x4*)src;
  f32x4 a1 = *(const f32x4*)(src + 4);
  bf16x8 fr;
  fr[0] = (__bf16)a0[0]; fr[1] = (__bf16)a0[1]; fr[2] = (__bf16)a0[2]; fr[3] = (__bf16)a0[3];
  fr[4] = (__bf16)a1[0]; fr[5] = (__bf16)a1[1]; fr[6] = (__bf16)a1[2]; fr[7] = (__bf16)a1[3];
  return fr;
}

// async global->LDS, 16B per lane; LDS dest = wave-uniform base + lane*16
static __device__ __forceinline__ void gload_lds16(const bf16_t* g, bf16_t* l) {
  __builtin_amdgcn_global_load_lds(
      (const __attribute__((address_space(1))) unsigned int*)g,
      (__attribute__((address_space(3))) unsigned int*)l, 16, 0, 0);
}

// ============================================================
// Kernel 0: composite/bf16 weights.
//  y=0: Wqkvb[0:128]   = bf16(Wa@Wq)      (qa path)
//  y=1: Wqkvb[128:256] = bf16(Wa@Wk)      (ka path)
//  y=2: Wdab           = bf16(Wa@Wd2), cb = ba + Wa@bd2 (fp32)
//  y=3: Wqkvb[256:384] = bf16(Wv)
//  y=4: Wf1b = bf16(Wf1)   y=5: Wf2b = bf16(Wf2)
// grid (8,6), block 256
// ============================================================
__global__ __launch_bounds__(256) void compw_k(
    const float* __restrict__ Wa, const float* __restrict__ Wq,
    const float* __restrict__ Wk, const float* __restrict__ Wd2,
    const float* __restrict__ ba, const float* __restrict__ bd2,
    const float* __restrict__ Wv, const float* __restrict__ Wf1, const float* __restrict__ Wf2,
    bf16_t* __restrict__ Wqkvb, bf16_t* __restrict__ Wdab, float* __restrict__ cb,
    bf16_t* __restrict__ Wf1b, bf16_t* __restrict__ Wf2b) {
  __shared__ float Bs[64 * 128];
  int t = threadIdx.x;
  int mat = blockIdx.y;
  if (mat >= 3) {  // plain bf16 copies
    int nel = (mat == 3) ? 16384 : 65536;
    const float* S = mat == 3 ? Wv : (mat == 4 ? Wf1 : Wf2);
    bf16_t* D = mat == 3 ? (Wqkvb + 256 * 128) : (mat == 4 ? Wf1b : Wf2b);
    for (int i = blockIdx.x * 256 + t; i * 8 < nel; i += 2048)
      *(bf16x8*)(D + i * 8) = cvt8(S + i * 8);
    return;
  }
  const float* B = mat == 0 ? Wq : mat == 1 ? Wk : Wd2;
  bf16_t* O = mat == 0 ? Wqkvb : mat == 1 ? (Wqkvb + 128 * 128) : Wdab;
  int row = blockIdx.x * 16 + (t >> 4);
  int c0 = (t & 15) * 8;
  const float* ar = Wa + row * 128;
  float acc[8] = {};
  for (int half = 0; half < 2; ++half) {
    __syncthreads();
    for (int i = t; i < 64 * 128 / 4; i += 256)
      ((f32x4*)Bs)[i] = ((const f32x4*)(B + half * 64 * 128))[i];
    __syncthreads();
    #pragma unroll 4
    for (int e = 0; e < 64; ++e) {
      float av = ar[half * 64 + e];
      #pragma unroll
      for (int j = 0; j < 8; ++j) acc[j] = fmaf(av, Bs[e * 128 + c0 + j], acc[j]);
    }
  }
  #pragma unroll
  for (int j = 0; j < 8; ++j) O[row * 128 + c0 + j] = (__bf16)acc[j];
  if (mat == 2 && blockIdx.x == 0 && t < 128) {
    float s = 0.f;
    for (int e = 0; e < 128; ++e) s = fmaf(Wa[t * 128 + e], bd2[e], s);
    cb[t] = ba[t] + s;
  }
}

// ============================================================
// Kernel 1: in_proj + LN1, MFMA-based (unchanged from R6).
// ============================================================
__global__ __launch_bounds__(256) void inproj_ln_k(
    const float* __restrict__ x, const float* __restrict__ Win, const float* __restrict__ bin,
    const float* __restrict__ g1, const float* __restrict__ b1,
    float* __restrict__ h, bf16_t* __restrict__ hnb) {
  __shared__ bf16_t As[64 * 72];
  __shared__ bf16_t Bs[128 * 72];
  __shared__ float hs[64 * 132];
  int t = threadIdx.x;
  int lane = t & 63, w = t >> 6, quad = lane >> 4, l15 = lane & 15;
  int mBase = remap256(blockIdx.x) * 64;
  int b = mBase >> 11, n0 = mBase & (NN - 1);
  const float* xb = x + (size_t)b * CIN * NN;
  {
    int k = t >> 2, part = t & 3;
    #pragma unroll
    for (int i = 0; i < 4; ++i) {
      f32x4 v = *(const f32x4*)(xb + (size_t)k * NN + n0 + part * 16 + i * 4);
      #pragma unroll
      for (int j2 = 0; j2 < 4; ++j2) As[(part * 16 + i * 4 + j2) * 72 + k] = (__bf16)v[j2];
    }
  }
  {
    int row = t >> 1, seg = (t & 1) * 32;
    #pragma unroll
    for (int i = 0; i < 4; ++i)
      *(bf16x8*)(&Bs[row * 72 + seg + i * 8]) = cvt8(Win + (size_t)row * CIN + seg + i * 8);
  }
  __syncthreads();
  f32x4 acc[2][4] = {};
  #pragma unroll
  for (int s = 0; s < 2; ++s) {
    bf16x8 af[4];
    #pragma unroll
    for (int mt = 0; mt < 4; ++mt)
      af[mt] = *(const bf16x8*)(&As[(mt * 16 + l15) * 72 + s * 32 + quad * 8]);
    #pragma unroll
    for (int t2 = 0; t2 < 2; ++t2) {
      bf16x8 bfr = *(const bf16x8*)(&Bs[((w * 2 + t2) * 16 + l15) * 72 + s * 32 + quad * 8]);
      #pragma unroll
      for (int mt = 0; mt < 4; ++mt) acc[t2][mt] = MFMA16(af[mt], bfr, acc[t2][mt]);
    }
  }
  #pragma unroll
  for (int t2 = 0; t2 < 2; ++t2) {
    int col = (w * 2 + t2) * 16 + l15;
    float bv = bin[col];
    #pragma unroll
    for (int mt = 0; mt < 4; ++mt)
      #pragma unroll
      for (int reg = 0; reg < 4; ++reg)
        hs[(mt * 16 + quad * 4 + reg) * 132 + col] = acc[t2][mt][reg] + bv;
  }
  __syncthreads();
  {
    int row = t >> 2, c0 = (t & 3) * 32;
    float v[32];
    #pragma unroll
    for (int i = 0; i < 8; ++i) *(f32x4*)(v + i * 4) = *(const f32x4*)(&hs[row * 132 + c0 + i * 4]);
    float s1 = 0.f, s2 = 0.f;
    #pragma unroll
    for (int i = 0; i < 32; ++i) { s1 += v[i]; s2 += v[i] * v[i]; }
    s1 += __shfl_xor(s1, 1); s1 += __shfl_xor(s1, 2);
    s2 += __shfl_xor(s2, 1); s2 += __shfl_xor(s2, 2);
    float mu = s1 * (1.f / CC);
    float var = s2 * (1.f / CC) - mu * mu;
    float rs = rsqrtf(var + 1e-5f);
    float* hrow = h + (size_t)(mBase + row) * CC + c0;
    #pragma unroll
    for (int i = 0; i < 8; ++i) *(f32x4*)(hrow + i * 4) = *(const f32x4*)(v + i * 4);
    bf16_t* hnrow = hnb + (size_t)(mBase + row) * CC + c0;
    #pragma unroll
    for (int i = 0; i < 4; ++i) {
      f32x4 g4a = ((const f32x4*)g1)[(c0 >> 2) + i * 2],     g4b = ((const f32x4*)g1)[(c0 >> 2) + i * 2 + 1];
      f32x4 b4a = ((const f32x4*)b1)[(c0 >> 2) + i * 2],     b4b = ((const f32x4*)b1)[(c0 >> 2) + i * 2 + 1];
      bf16x8 o;
      #pragma unroll
      for (int j = 0; j < 4; ++j) o[j]     = (__bf16)((v[i * 8 + j]     - mu) * rs * g4a[j] + b4a[j]);
      #pragma unroll
      for (int j = 0; j < 4; ++j) o[4 + j] = (__bf16)((v[i * 8 + 4 + j] - mu) * rs * g4b[j] + b4b[j]);
      *(bf16x8*)(hnrow + i * 8) = o;
    }
  }
}

// ============================================================
// Kernel 3: KNN (unchanged from R6).
// ============================================================
static __device__ __forceinline__ void cas(double& a, double& b) {
  double lo = fmin(a, b), hi = fmax(a, b); a = lo; b = hi;
}
#define S8(K,o) \
  cas(K[o+0],K[o+1]); cas(K[o+2],K[o+3]); cas(K[o+4],K[o+5]); cas(K[o+6],K[o+7]); \
  cas(K[o+0],K[o+2]); cas(K[o+1],K[o+3]); cas(K[o+4],K[o+6]); cas(K[o+5],K[o+7]); \
  cas(K[o+1],K[o+2]); cas(K[o+5],K[o+6]); \
  cas(K[o+0],K[o+4]); cas(K[o+1],K[o+5]); cas(K[o+2],K[o+6]); cas(K[o+3],K[o+7]); \
  cas(K[o+2],K[o+4]); cas(K[o+3],K[o+5]); \
  cas(K[o+1],K[o+2]); cas(K[o+3],K[o+4]); cas(K[o+5],K[o+6]);
#define M8(K,a,b) \
  K[a+0]=fmin(K[a+0],K[b+7]); K[a+1]=fmin(K[a+1],K[b+6]); K[a+2]=fmin(K[a+2],K[b+5]); K[a+3]=fmin(K[a+3],K[b+4]); \
  K[a+4]=fmin(K[a+4],K[b+3]); K[a+5]=fmin(K[a+5],K[b+2]); K[a+6]=fmin(K[a+6],K[b+1]); K[a+7]=fmin(K[a+7],K[b+0]); \
  cas(K[a+0],K[a+4]); cas(K[a+1],K[a+5]); cas(K[a+2],K[a+6]); cas(K[a+3],K[a+7]); \
  cas(K[a+0],K[a+2]); cas(K[a+1],K[a+3]); cas(K[a+4],K[a+6]); cas(K[a+5],K[a+7]); \
  cas(K[a+0],K[a+1]); cas(K[a+2],K[a+3]); cas(K[a+4],K[a+5]); cas(K[a+6],K[a+7]);

__global__ __launch_bounds__(256) void knn_k(const float* __restrict__ p, int* __restrict__ idxo) {
  __shared__ float px[NN], py[NN], pz[NN];
  int t = threadIdx.x;
  int b = blockIdx.x >> 9;
  int g = blockIdx.x & 511;
  const float* pb = p + (size_t)b * 3 * NN;
  for (int i = t; i < NN; i += 256) { px[i] = pb[i]; py[i] = pb[NN + i]; pz[i] = pb[2 * NN + i]; }
  __syncthreads();
  int w = t >> 6, lane = t & 63;
  int n = g * 4 + w;
  float pnx = px[n], pny = py[n], pnz = pz[n];
  double key[32];
  #pragma unroll
  for (int s = 0; s < 32; ++s) {
    int m = s * 64 + lane;
    float dx = pnx - px[m], dy = pny - py[m], dz = pnz - pz[m];
    float dist = dx * dx + dy * dy + dz * dz;
    unsigned db = (m == n) ? 0x7F800000u : __float_as_uint(dist);
    key[s] = __hiloint2double((int)db, m);
  }
  S8(key, 0); S8(key, 8); S8(key, 16); S8(key, 24);
  M8(key, 0, 8); M8(key, 16, 24); M8(key, 0, 16);
  const double DINF = __hiloint2double(0x7F900000, 0);
  int* myout = idxo + ((size_t)b * NN + n) * KNB;
  #pragma unroll 1
  for (int r = 0; r < 16; ++r) {
    double gm = key[0];
    #pragma unroll
    for (int off = 1; off < 64; off <<= 1) {
      double o = __shfl_xor(gm, off);
      gm = fmin(gm, o);
    }
    if (lane == 0) myout[r] = __double2loint(gm);
    bool win = (key[0] == gm);
    key[0] = win ? key[1] : key[0];
    key[1] = win ? key[2] : key[1];
    key[2] = win ? key[3] : key[2];
    key[3] = win ? key[4] : key[3];
    key[4] = win ? key[5] : key[4];
    key[5] = win ? key[6] : key[5];
    key[6] = win ? key[7] : key[6];
    key[7] = win ? DINF   : key[7];
  }
}

// ============================================================
// m97-style 128x128 GEMM, BK=32, global_load_lds width=16, A & W bf16.
// 4 waves: wave w owns quadrant (wm=(w&1)*64, wn=(w>>1)*64), 4x4 acc.
// EPI: 1 relu->bf16, 2 +resid transposed fp32 [B,C,N], 3 bf16.
// LDS layout MUST be raw 128x32 (global_load_lds: base + lane*16).
// ============================================================
template<int EPI>
static __device__ __forceinline__ void gemm128_body(
    const bf16_t* __restrict__ A, const bf16_t* __restrict__ Wb, const float* __restrict__ bias,
    float* __restrict__ outF, bf16_t* __restrict__ outB, const float* __restrict__ resid,
    int mBase, int nBase, int Ncol, int Kdim) {
  __shared__ bf16_t As[128 * 32];
  __shared__ bf16_t Bs[128 * 32];
  int t = threadIdx.x;
  int lane = t & 63, w = t >> 6, quad = lane >> 4, l15 = lane & 15;
  int wm = (w & 1) * 64, wn = (w >> 1) * 64;
  int srow = lane >> 2, scol = (lane & 3) * 8;
  f32x4 acc[4][4] = {};
  for (int k0 = 0; k0 < Kdim; k0 += 32) {
    __syncthreads();
    #pragma unroll
    for (int i = 0; i < 2; ++i) {
      int rbase = w * 32 + i * 16;
      gload_lds16(A  + (size_t)(mBase + rbase + srow) * Kdim + k0 + scol, &As[rbase * 32]);
      gload_lds16(Wb + (size_t)(nBase + rbase + srow) * Kdim + k0 + scol, &Bs[rbase * 32]);
    }
    __syncthreads();
    bf16x8 af[4], bf[4];
    #pragma unroll
    for (int mt = 0; mt < 4; ++mt) af[mt] = *(const bf16x8*)(&As[(wm + mt * 16 + l15) * 32 + quad * 8]);
    #pragma unroll
    for (int nt = 0; nt < 4; ++nt) bf[nt] = *(const bf16x8*)(&Bs[(wn + nt * 16 + l15) * 32 + quad * 8]);
    #pragma unroll
    for (int mt = 0; mt < 4; ++mt)
      #pragma unroll
      for (int nt = 0; nt < 4; ++nt)
        acc[mt][nt] = MFMA16(af[mt], bf[nt], acc[mt][nt]);
  }
  #pragma unroll
  for (int nt = 0; nt < 4; ++nt) {
    int n = nBase + wn + nt * 16 + l15;
    float bv = bias ? bias[n] : 0.f;
    #pragma unroll
    for (int mt = 0; mt < 4; ++mt) {
      #pragma unroll
      for (int reg = 0; reg < 4; ++reg) {
        int m = mBase + wm + mt * 16 + quad * 4 + reg;
        float val = acc[mt][nt][reg] + bv;
        if (EPI == 1) {
          outB[(size_t)m * Ncol + n] = (__bf16)fmaxf(val, 0.f);
        } else if (EPI == 3) {
          outB[(size_t)m * Ncol + n] = (__bf16)val;
        } else {
          val += resid[(size_t)m * CC + n];
          int bo = m >> 11, np = m & (NN - 1);
          outF[((size_t)bo * CC + n) * NN + np] = val;
        }
      }
    }
  }
}

template<int EPI>
__global__ __launch_bounds__(256) void gemm128_k(
    const bf16_t* __restrict__ A, const bf16_t* __restrict__ Wb, const float* __restrict__ bias,
    float* __restrict__ outF, bf16_t* __restrict__ outB, const float* __restrict__ resid,
    int Ncol, int Kdim) {
  gemm128_body<EPI>(A, Wb, bias, outF, outB, resid,
                    remap128(blockIdx.x) * 128, blockIdx.y * 128, Ncol, Kdim);
}

// fused q/k/v: y picks slice of Wqkvb and output third of qkv buffer (all bf16)
__global__ __launch_bounds__(256) void gemm_qkv_k(
    const bf16_t* __restrict__ hnb, const bf16_t* __restrict__ Wqkvb, bf16_t* __restrict__ qkv) {
  int y = blockIdx.y;
  gemm128_body<3>(hnb, Wqkvb + (size_t)y * 128 * CC, nullptr, nullptr,
                  qkv + (size_t)y * BNT * CC, nullptr,
                  remap128(blockIdx.x) * 128, 0, CC, CC);
}

// ============================================================
// Kernel 5: fused neighbor attention v5 (R7 + early gathers):
// all idx-dependent gathers issue immediately after the staging barrier,
// overlapping the ~1k-cycle t-compute/MFMA phase instead of following it.
// qa now bf16; Wda read as bf16 (Wdab).
// ============================================================
__global__ __launch_bounds__(256, 3) void attn_k(
    const bf16_t* __restrict__ qabuf, const bf16_t* __restrict__ kabuf, const bf16_t* __restrict__ vbuf,
    const float* __restrict__ p, const int* __restrict__ idx,
    const float* __restrict__ Wd1, const float* __restrict__ bd1,
    const float* __restrict__ Wd2, const bf16_t* __restrict__ Wdab,
    const float* __restrict__ cb, const float* __restrict__ bd2,
    const float* __restrict__ g2, const float* __restrict__ b2,
    const float* __restrict__ h, float* __restrict__ hres, bf16_t* __restrict__ h2) {
  __shared__ f32x4 wd1s[128];          // {Wd1[c][0..2], bd1[c]}
  __shared__ f32x4 rels4[64];          // {rx,ry,rz,0}
  __shared__ int idxs[64];
  __shared__ float hrs[4 * 128];
  int t = threadIdx.x;
  int lane = t & 63, w = t >> 6, quad = lane >> 4, l15 = lane & 15;
  int batch = blockIdx.x & 7, grp = blockIdx.x >> 3;
  int bn0 = batch * NN + grp * 4;
  const float* pb = p + (size_t)batch * 3 * NN;
  int col0 = w * 32 + l15;
  int col1 = col0 + 16;

  // persistent B fragments
  bf16x8 Bd[2][4], Bl[2][4];
  #pragma unroll
  for (int t2 = 0; t2 < 2; ++t2) {
    int row = w * 32 + t2 * 16 + l15;
    #pragma unroll
    for (int s = 0; s < 4; ++s) {
      Bd[t2][s] = cvt8(Wd2 + (size_t)row * CC + s * 32 + quad * 8);
      Bl[t2][s] = *(const bf16x8*)(Wdab + (size_t)row * CC + s * 32 + quad * 8);
    }
  }

  // phase 0: idx, rel, wd1 staging
  if (t < 64) {
    int jj = idx[(size_t)bn0 * KNB + t];
    idxs[t] = jj;
    int npt = grp * 4 + (t >> 4);
    f32x4 rv;
    rv[0] = pb[npt]          - pb[jj];
    rv[1] = pb[NN + npt]     - pb[NN + jj];
    rv[2] = pb[2 * NN + npt] - pb[2 * NN + jj];
    rv[3] = 0.f;
    rels4[t] = rv;
  }
  if (t < 128) {
    f32x4 wv;
    wv[0] = Wd1[t * 3]; wv[1] = Wd1[t * 3 + 1]; wv[2] = Wd1[t * 3 + 2]; wv[3] = bd1[t];
    wd1s[t] = wv;
  }
  __syncthreads();

  // EARLY gathers: issue everything idx-dependent now; latency overlaps
  // the t-compute + double MFMA chain below.
  float qv[2][4];
  #pragma unroll
  for (int mt = 0; mt < 4; ++mt) {
    qv[0][mt] = (float)qabuf[(size_t)(bn0 + mt) * CC + col0];
    qv[1][mt] = (float)qabuf[(size_t)(bn0 + mt) * CC + col1];
  }
  float kav[2][4][4], vv[2][4][4];
  #pragma unroll
  for (int mt = 0; mt < 4; ++mt)
    #pragma unroll
    for (int reg = 0; reg < 4; ++reg) {
      size_t base = (size_t)(batch * NN + idxs[mt * 16 + quad * 4 + reg]) * CC;
      kav[0][mt][reg] = (float)kabuf[base + col0];
      kav[1][mt][reg] = (float)kabuf[base + col1];
      vv[0][mt][reg]  = (float)vbuf[base + col0];
      vv[1][mt][reg]  = (float)vbuf[base + col1];
    }
  float hv[2][4];
  if (quad == 0) {
    #pragma unroll
    for (int mt = 0; mt < 4; ++mt) {
      hv[0][mt] = h[(size_t)(bn0 + mt) * CC + col0];
      hv[1][mt] = h[(size_t)(bn0 + mt) * CC + col1];
    }
  }

  // t-fragments in registers (A-layout) feeding BOTH MFMA chains
  f32x4 relv[4];
  #pragma unroll
  for (int mt = 0; mt < 4; ++mt) relv[mt] = rels4[mt * 16 + l15];
  f32x4 accd[2][4] = {};   // d  = t @ Wd2^T
  f32x4 accl[2][4] = {};   // la = t @ Wda^T
  #pragma unroll
  for (int s = 0; s < 4; ++s) {
    bf16x8 af[4];
    #pragma unroll
    for (int j = 0; j < 8; ++j) {
      f32x4 wv = wd1s[s * 32 + quad * 8 + j];
      #pragma unroll
      for (int mt = 0; mt < 4; ++mt) {
        float tv = fmaf(wv[0], relv[mt][0], fmaf(wv[1], relv[mt][1], fmaf(wv[2], relv[mt][2], wv[3])));
        af[mt][j] = (__bf16)fmaxf(tv, 0.f);
      }
    }
    #pragma unroll
    for (int t2 = 0; t2 < 2; ++t2)
      #pragma unroll
      for (int mt = 0; mt < 4; ++mt) {
        accd[t2][mt] = MFMA16(af[mt], Bd[t2][s], accd[t2][mt]);
        accl[t2][mt] = MFMA16(af[mt], Bl[t2][s], accl[t2][mt]);
      }
  }

  // logits = qa - ka + la + cb ; softmax over j ; y = sum a*(v+d)
  #pragma unroll
  for (int t2 = 0; t2 < 2; ++t2) {
    int col = t2 ? col1 : col0;
    float cbv = cb[col];
    float b2v = bd2[col];
    #pragma unroll
    for (int mt = 0; mt < 4; ++mt) {
      float qc = qv[t2][mt] + cbv;
      float lv0 = qc - kav[t2][mt][0] + accl[t2][mt][0];
      float lv1 = qc - kav[t2][mt][1] + accl[t2][mt][1];
      float lv2 = qc - kav[t2][mt][2] + accl[t2][mt][2];
      float lv3 = qc - kav[t2][mt][3] + accl[t2][mt][3];
      float mx = fmaxf(fmaxf(lv0, lv1), fmaxf(lv2, lv3));
      mx = fmaxf(mx, __shfl_xor(mx, 16));
      mx = fmaxf(mx, __shfl_xor(mx, 32));
      float e0 = __expf(lv0 - mx), e1 = __expf(lv1 - mx);
      float e2 = __expf(lv2 - mx), e3 = __expf(lv3 - mx);
      float ss = e0 + e1 + e2 + e3;
      ss += __shfl_xor(ss, 16); ss += __shfl_xor(ss, 32);
      float yv = e0 * (vv[t2][mt][0] + accd[t2][mt][0] + b2v)
               + e1 * (vv[t2][mt][1] + accd[t2][mt][1] + b2v)
               + e2 * (vv[t2][mt][2] + accd[t2][mt][2] + b2v)
               + e3 * (vv[t2][mt][3] + accd[t2][mt][3] + b2v);
      yv += __shfl_xor(yv, 16); yv += __shfl_xor(yv, 32);
      if (quad == 0) {
        float hvv = hv[t2][mt] + yv / ss;
        hres[(size_t)(bn0 + mt) * CC + col] = hvv;
        hrs[mt * 128 + col] = hvv;
      }
    }
  }
  __syncthreads();

  // fused LN2: wave w normalizes point w, writes h2 bf16
  {
    int c0 = lane * 2;
    float v0 = hrs[w * 128 + c0], v1 = hrs[w * 128 + c0 + 1];
    float s1 = v0 + v1, s2 = v0 * v0 + v1 * v1;
    #pragma unroll
    for (int off = 1; off < 64; off <<= 1) { s1 += __shfl_xor(s1, off); s2 += __shfl_xor(s2, off); }
    float mu = s1 * (1.f / CC);
    float var = s2 * (1.f / CC) - mu * mu;
    float rs = rsqrtf(var + 1e-5f);
    bf16x2 o;
    o[0] = (__bf16)((v0 - mu) * rs * g2[c0] + b2[c0]);
    o[1] = (__bf16)((v1 - mu) * rs * g2[c0 + 1] + b2[c0 + 1]);
    *(bf16x2*)(h2 + (size_t)(bn0 + w) * CC + c0) = o;
  }
}

// ============================================================
extern "C" void kernel_launch(void* const* d_in, const int* in_sizes, int n_in,
                              void* d_out, int out_size, void* d_ws, size_t ws_size,
                              hipStream_t stream) {
  const float* x   = (const float*)d_in[0];
  const float* p   = (const float*)d_in[1];
  const float* Win = (const float*)d_in[2];
  const float* bin = (const float*)d_in[3];
  const float* Wq  = (const float*)d_in[4];
  const float* Wk  = (const float*)d_in[5];
  const float* Wv  = (const float*)d_in[6];
  const float* Wd1 = (const float*)d_in[7];
  const float* bd1 = (const float*)d_in[8];
  const float* Wd2 = (const float*)d_in[9];
  const float* bd2 = (const float*)d_in[10];
  const float* Wa  = (const float*)d_in[11];
  const float* ba  = (const float*)d_in[12];
  const float* g1  = (const float*)d_in[13];
  const float* b1  = (const float*)d_in[14];
  const float* g2  = (const float*)d_in[15];
  const float* b2  = (const float*)d_in[16];
  const float* Wf1 = (const float*)d_in[17];
  const float* bf1 = (const float*)d_in[18];
  const float* Wf2 = (const float*)d_in[19];
  const float* bf2 = (const float*)d_in[20];
  float* out = (float*)d_out;

  // workspace layout (floats; SZ = BNT*CC = 2,097,152):
  //  [0,SZ)        h fp32 (residual 1)
  //  [SZ,2SZ)      hnb bf16 (first half) -> hres fp32 after qkv consumed
  //  [2SZ,3.5SZ)   qkv bf16 (qa|ka|v, 3*SZ elems) -> g bf16 [2SZ,4SZ) after attn
  //  [4SZ,4.5SZ)   h2 bf16
  //  [4.5SZ,...)   idx | Wqkvb | Wdab | Wf1b | Wf2b | cb       (~39 MB total)
  const size_t SZ = (size_t)BNT * CC;
  float* wsf = (float*)d_ws;
  float*  h    = wsf;
  bf16_t* hnb  = (bf16_t*)(wsf + SZ);
  float*  hres = wsf + SZ;
  bf16_t* qkv  = (bf16_t*)(wsf + 2 * SZ);
  bf16_t* g    = (bf16_t*)(wsf + 2 * SZ);
  bf16_t* h2   = (bf16_t*)(wsf + 4 * SZ);
  int*    idxw = (int*)(wsf + 4 * SZ + SZ / 2);
  bf16_t* Wqkvb = (bf16_t*)(wsf + 4 * SZ + SZ / 2 + SZ / 8);
  bf16_t* Wdab  = Wqkvb + 384 * 128;
  bf16_t* Wf1b  = Wdab + 128 * 128;
  bf16_t* Wf2b  = Wf1b + 512 * 128;
  float*  cbv   = (float*)(Wf2b + 128 * 512);

  compw_k<<<dim3(8, 6), 256, 0, stream>>>(Wa, Wq, Wk, Wd2, ba, bd2, Wv, Wf1, Wf2,
                                          Wqkvb, Wdab, cbv, Wf1b, Wf2b);
  inproj_ln_k<<<BNT / 64, 256, 0, stream>>>(x, Win, bin, g1, b1, h, hnb);
  knn_k<<<BB * (NN / 4), 256, 0, stream>>>(p, idxw);
  gemm_qkv_k<<<dim3(BNT / 128, 3), 256, 0, stream>>>(hnb, Wqkvb, qkv);
  attn_k<<<BNT / 4, 256, 0, stream>>>(qkv, qkv + SZ, qkv + 2 * SZ, p, idxw,
                                      Wd1, bd1, Wd2, Wdab, cbv, bd2,
                                      g2, b2, h, hres, h2);
  gemm128_k<1><<<dim3(BNT / 128, 4), 256, 0, stream>>>(h2, Wf1b, bf1, nullptr, g, nullptr, 4 * CC, CC);
  gemm128_k<2><<<dim3(BNT / 128, 1), 256, 0, stream>>>(g, Wf2b, bf2, out, nullptr, hres, CC, 4 * CC);
}

// Round 10
// 295.113 us; speedup vs baseline: 1.4678x; 1.4678x over previous
//
#include <hip/hip_runtime.h>

typedef __bf16 bf16_t;
typedef __bf16 bf16x8 __attribute__((ext_vector_type(8)));
typedef __bf16 bf16x2 __attribute__((ext_vector_type(2)));
typedef float  f32x4  __attribute__((ext_vector_type(4)));

#define MFMA16(a,b,c) __builtin_amdgcn_mfma_f32_16x16x32_bf16((a),(b),(c),0,0,0)

// ---- constants (problem is fixed-shape) ----
#define BB 8
#define NN 2048
#define CC 128
#define CIN 64
#define KNB 16            // neighbors
#define BNT (BB*NN)       // 16384 points

// XCD affinity: batch a block touches == blockIdx%8 == its XCD (R6-verified:
// cut attn FETCH 38->13.5 MB).
static __device__ __forceinline__ int remap256(int x) { return ((x & 7) << 5) | (x >> 3); }

static __device__ __forceinline__ bf16x8 cvt8(const float* src) {
  f32x4 a0 = *(const f32x4*)src;
  f32x4 a1 = *(const f32x4*)(src + 4);
  bf16x8 fr;
  fr[0] = (__bf16)a0[0]; fr[1] = (__bf16)a0[1]; fr[2] = (__bf16)a0[2]; fr[3] = (__bf16)a0[3];
  fr[4] = (__bf16)a1[0]; fr[5] = (__bf16)a1[1]; fr[6] = (__bf16)a1[2]; fr[7] = (__bf16)a1[3];
  return fr;
}

// ============================================================
// Kernel 1: in_proj + LN1, MFMA-based (R6 verbatim).
// ============================================================
__global__ __launch_bounds__(256) void inproj_ln_k(
    const float* __restrict__ x, const float* __restrict__ Win, const float* __restrict__ bin,
    const float* __restrict__ g1, const float* __restrict__ b1,
    float* __restrict__ h, bf16_t* __restrict__ hnb) {
  __shared__ bf16_t As[64 * 72];
  __shared__ bf16_t Bs[128 * 72];
  __shared__ float hs[64 * 132];
  int t = threadIdx.x;
  int lane = t & 63, w = t >> 6, quad = lane >> 4, l15 = lane & 15;
  int mBase = remap256(blockIdx.x) * 64;
  int b = mBase >> 11, n0 = mBase & (NN - 1);
  const float* xb = x + (size_t)b * CIN * NN;
  {
    int k = t >> 2, part = t & 3;
    #pragma unroll
    for (int i = 0; i < 4; ++i) {
      f32x4 v = *(const f32x4*)(xb + (size_t)k * NN + n0 + part * 16 + i * 4);
      #pragma unroll
      for (int j2 = 0; j2 < 4; ++j2) As[(part * 16 + i * 4 + j2) * 72 + k] = (__bf16)v[j2];
    }
  }
  {
    int row = t >> 1, seg = (t & 1) * 32;
    #pragma unroll
    for (int i = 0; i < 4; ++i)
      *(bf16x8*)(&Bs[row * 72 + seg + i * 8]) = cvt8(Win + (size_t)row * CIN + seg + i * 8);
  }
  __syncthreads();
  f32x4 acc[2][4] = {};
  #pragma unroll
  for (int s = 0; s < 2; ++s) {
    bf16x8 af[4];
    #pragma unroll
    for (int mt = 0; mt < 4; ++mt)
      af[mt] = *(const bf16x8*)(&As[(mt * 16 + l15) * 72 + s * 32 + quad * 8]);
    #pragma unroll
    for (int t2 = 0; t2 < 2; ++t2) {
      bf16x8 bfr = *(const bf16x8*)(&Bs[((w * 2 + t2) * 16 + l15) * 72 + s * 32 + quad * 8]);
      #pragma unroll
      for (int mt = 0; mt < 4; ++mt) acc[t2][mt] = MFMA16(af[mt], bfr, acc[t2][mt]);
    }
  }
  #pragma unroll
  for (int t2 = 0; t2 < 2; ++t2) {
    int col = (w * 2 + t2) * 16 + l15;
    float bv = bin[col];
    #pragma unroll
    for (int mt = 0; mt < 4; ++mt)
      #pragma unroll
      for (int reg = 0; reg < 4; ++reg)
        hs[(mt * 16 + quad * 4 + reg) * 132 + col] = acc[t2][mt][reg] + bv;
  }
  __syncthreads();
  {
    int row = t >> 2, c0 = (t & 3) * 32;
    float v[32];
    #pragma unroll
    for (int i = 0; i < 8; ++i) *(f32x4*)(v + i * 4) = *(const f32x4*)(&hs[row * 132 + c0 + i * 4]);
    float s1 = 0.f, s2 = 0.f;
    #pragma unroll
    for (int i = 0; i < 32; ++i) { s1 += v[i]; s2 += v[i] * v[i]; }
    s1 += __shfl_xor(s1, 1); s1 += __shfl_xor(s1, 2);
    s2 += __shfl_xor(s2, 1); s2 += __shfl_xor(s2, 2);
    float mu = s1 * (1.f / CC);
    float var = s2 * (1.f / CC) - mu * mu;
    float rs = rsqrtf(var + 1e-5f);
    float* hrow = h + (size_t)(mBase + row) * CC + c0;
    #pragma unroll
    for (int i = 0; i < 8; ++i) *(f32x4*)(hrow + i * 4) = *(const f32x4*)(v + i * 4);
    bf16_t* hnrow = hnb + (size_t)(mBase + row) * CC + c0;
    #pragma unroll
    for (int i = 0; i < 4; ++i) {
      f32x4 g4a = ((const f32x4*)g1)[(c0 >> 2) + i * 2],     g4b = ((const f32x4*)g1)[(c0 >> 2) + i * 2 + 1];
      f32x4 b4a = ((const f32x4*)b1)[(c0 >> 2) + i * 2],     b4b = ((const f32x4*)b1)[(c0 >> 2) + i * 2 + 1];
      bf16x8 o;
      #pragma unroll
      for (int j = 0; j < 4; ++j) o[j]     = (__bf16)((v[i * 8 + j]     - mu) * rs * g4a[j] + b4a[j]);
      #pragma unroll
      for (int j = 0; j < 4; ++j) o[4 + j] = (__bf16)((v[i * 8 + 4 + j] - mu) * rs * g4b[j] + b4b[j]);
      *(bf16x8*)(hnrow + i * 8) = o;
    }
  }
}

// ============================================================
// KNN body (R6 verbatim, LDS passed in): packed (dist,idx) doubles,
// bitonic top-8 per lane, 16 butterfly extraction rounds.
// ============================================================
static __device__ __forceinline__ void cas(double& a, double& b) {
  double lo = fmin(a, b), hi = fmax(a, b); a = lo; b = hi;
}
#define S8(K,o) \
  cas(K[o+0],K[o+1]); cas(K[o+2],K[o+3]); cas(K[o+4],K[o+5]); cas(K[o+6],K[o+7]); \
  cas(K[o+0],K[o+2]); cas(K[o+1],K[o+3]); cas(K[o+4],K[o+6]); cas(K[o+5],K[o+7]); \
  cas(K[o+1],K[o+2]); cas(K[o+5],K[o+6]); \
  cas(K[o+0],K[o+4]); cas(K[o+1],K[o+5]); cas(K[o+2],K[o+6]); cas(K[o+3],K[o+7]); \
  cas(K[o+2],K[o+4]); cas(K[o+3],K[o+5]); \
  cas(K[o+1],K[o+2]); cas(K[o+3],K[o+4]); cas(K[o+5],K[o+6]);
#define M8(K,a,b) \
  K[a+0]=fmin(K[a+0],K[b+7]); K[a+1]=fmin(K[a+1],K[b+6]); K[a+2]=fmin(K[a+2],K[b+5]); K[a+3]=fmin(K[a+3],K[b+4]); \
  K[a+4]=fmin(K[a+4],K[b+3]); K[a+5]=fmin(K[a+5],K[b+2]); K[a+6]=fmin(K[a+6],K[b+1]); K[a+7]=fmin(K[a+7],K[b+0]); \
  cas(K[a+0],K[a+4]); cas(K[a+1],K[a+5]); cas(K[a+2],K[a+6]); cas(K[a+3],K[a+7]); \
  cas(K[a+0],K[a+2]); cas(K[a+1],K[a+3]); cas(K[a+4],K[a+6]); cas(K[a+5],K[a+7]); \
  cas(K[a+0],K[a+1]); cas(K[a+2],K[a+3]); cas(K[a+4],K[a+5]); cas(K[a+6],K[a+7]);

static __device__ void knn_impl(float* sp, const float* __restrict__ p,
                                int* __restrict__ idxo, int bid) {
  float* px = sp; float* py = sp + NN; float* pz = sp + 2 * NN;
  int t = threadIdx.x;
  int b = bid >> 9;
  int g = bid & 511;
  const float* pb = p + (size_t)b * 3 * NN;
  for (int i = t; i < NN; i += 256) { px[i] = pb[i]; py[i] = pb[NN + i]; pz[i] = pb[2 * NN + i]; }
  __syncthreads();
  int w = t >> 6, lane = t & 63;
  int n = g * 4 + w;
  float pnx = px[n], pny = py[n], pnz = pz[n];
  double key[32];
  #pragma unroll
  for (int s = 0; s < 32; ++s) {
    int m = s * 64 + lane;
    float dx = pnx - px[m], dy = pny - py[m], dz = pnz - pz[m];
    float dist = dx * dx + dy * dy + dz * dz;
    unsigned db = (m == n) ? 0x7F800000u : __float_as_uint(dist);
    key[s] = __hiloint2double((int)db, m);
  }
  S8(key, 0); S8(key, 8); S8(key, 16); S8(key, 24);
  M8(key, 0, 8); M8(key, 16, 24); M8(key, 0, 16);
  const double DINF = __hiloint2double(0x7F900000, 0);
  int* myout = idxo + ((size_t)b * NN + n) * KNB;
  #pragma unroll 1
  for (int r = 0; r < 16; ++r) {
    double gm = key[0];
    #pragma unroll
    for (int off = 1; off < 64; off <<= 1) {
      double o = __shfl_xor(gm, off);
      gm = fmin(gm, o);
    }
    if (lane == 0) myout[r] = __double2loint(gm);
    bool win = (key[0] == gm);
    key[0] = win ? key[1] : key[0];
    key[1] = win ? key[2] : key[1];
    key[2] = win ? key[3] : key[2];
    key[3] = win ? key[4] : key[3];
    key[4] = win ? key[5] : key[4];
    key[5] = win ? key[6] : key[5];
    key[6] = win ? key[7] : key[6];
    key[7] = win ? DINF   : key[7];
  }
}

// ============================================================
// 64x64 GEMM body v2: stage the full K=128 panel once (64x136 bf16,
// pad->2-way bank aliasing = free), 2 barriers per 128-chunk instead of
// 8 (R6). MFMA accumulation order identical to R6 -> bit-identical.
// A bf16, W fp32 (cvt8 at stage). EPI: 0 fp32, 1 relu->bf16,
// 2 +resid transposed fp32 [B,C,N].
// ============================================================
template<int EPI>
static __device__ void gemm_body2(bf16_t* As, bf16_t* Bs,
    const bf16_t* __restrict__ Ab, const float* __restrict__ W, const float* __restrict__ bias,
    float* __restrict__ outF, bf16_t* __restrict__ outB, const float* __restrict__ resid,
    int mBase, int nBase, int Ncol, int Kdim) {
  int t = threadIdx.x;
  int lane = t & 63, w = t >> 6, quad = lane >> 4, l15 = lane & 15;
  int r = t >> 2, segbase = (t & 3) * 32;
  f32x4 acc[4] = {{0,0,0,0},{0,0,0,0},{0,0,0,0},{0,0,0,0}};
  for (int k0 = 0; k0 < Kdim; k0 += 128) {
    __syncthreads();
    #pragma unroll
    for (int i = 0; i < 4; ++i) {
      int seg = segbase + i * 8;
      *(bf16x8*)(&As[r * 136 + seg]) = *(const bf16x8*)(Ab + (size_t)(mBase + r) * Kdim + k0 + seg);
      *(bf16x8*)(&Bs[r * 136 + seg]) = cvt8(W + (size_t)(nBase + r) * Kdim + k0 + seg);
    }
    __syncthreads();
    #pragma unroll
    for (int s = 0; s < 4; ++s) {
      bf16x8 bfr = *(const bf16x8*)(&Bs[(w * 16 + l15) * 136 + s * 32 + quad * 8]);
      #pragma unroll
      for (int mt = 0; mt < 4; ++mt) {
        bf16x8 afr = *(const bf16x8*)(&As[(mt * 16 + l15) * 136 + s * 32 + quad * 8]);
        acc[mt] = MFMA16(afr, bfr, acc[mt]);
      }
    }
  }
  int n = nBase + w * 16 + l15;
  float bv = bias ? bias[n] : 0.f;
  #pragma unroll
  for (int mt = 0; mt < 4; ++mt) {
    #pragma unroll
    for (int reg = 0; reg < 4; ++reg) {
      int m = mBase + mt * 16 + quad * 4 + reg;
      float val = acc[mt][reg] + bv;
      if (EPI == 0) {
        outF[(size_t)m * Ncol + n] = val;
      } else if (EPI == 1) {
        outB[(size_t)m * Ncol + n] = (__bf16)fmaxf(val, 0.f);
      } else if (EPI == 3) {
        outB[(size_t)m * Ncol + n] = (__bf16)val;
      } else {
        val += resid[(size_t)m * CC + n];
        int bo = m >> 11, np = m & (NN - 1);
        outF[((size_t)bo * CC + n) * NN + np] = val;
      }
    }
  }
}

template<int EPI>
__global__ __launch_bounds__(256) void gemm_k(
    const bf16_t* __restrict__ Ab, const float* __restrict__ W, const float* __restrict__ bias,
    float* __restrict__ outF, bf16_t* __restrict__ outB, const float* __restrict__ resid,
    int Ncol, int Kdim) {
  __shared__ bf16_t As[64 * 136];
  __shared__ bf16_t Bs[64 * 136];
  gemm_body2<EPI>(As, Bs, Ab, W, bias, outF, outB, resid,
                  remap256(blockIdx.x) * 64, blockIdx.y * 64, Ncol, Kdim);
}

// ============================================================
// Fused knn + qkv dispatch. Blocks [0,4096): knn (pure VALU).
// Blocks [4096,5632): qkv GEMM (MFMA+mem). Independent work, union LDS
// (34816 B >= knn's 24576 B); complementary pipes co-schedule (m114).
// qkv block bx: yy=bx>>8 picks {Wq->q fp32, Wk->kb bf16, Wv->vb bf16}
// x (y&1) n-halves; xx=bx&255 with remap256 -> batch == XCD (bx%8==xx%8).
// ============================================================
__global__ __launch_bounds__(256) void knn_qkv_k(
    const float* __restrict__ p, int* __restrict__ idxo,
    const bf16_t* __restrict__ hnb,
    const float* __restrict__ Wq, const float* __restrict__ Wk, const float* __restrict__ Wv,
    float* __restrict__ q, bf16_t* __restrict__ kb, bf16_t* __restrict__ vb) {
  __shared__ __align__(16) char smem[2 * 64 * 136 * 2];
  if (blockIdx.x < 4096) {
    knn_impl((float*)smem, p, idxo, blockIdx.x);
  } else {
    bf16_t* As = (bf16_t*)smem;
    bf16_t* Bs = As + 64 * 136;
    int bx = blockIdx.x - 4096;
    int yy = bx >> 8, xx = bx & 255;
    int sel = yy >> 1;
    int mB = remap256(xx) * 64, nB = (yy & 1) * 64;
    if (sel == 0)      gemm_body2<0>(As, Bs, hnb, Wq, nullptr, q,  nullptr, nullptr, mB, nB, CC, CC);
    else if (sel == 1) gemm_body2<3>(As, Bs, hnb, Wk, nullptr, nullptr, kb, nullptr, mB, nB, CC, CC);
    else               gemm_body2<3>(As, Bs, hnb, Wv, nullptr, nullptr, vb, nullptr, mB, nB, CC, CC);
  }
}

// ============================================================
// Kernel 5: fused neighbor attention (R6 verbatim — 117 µs, absmax
// 0.03125 proven): batch = blockIdx&7 (XCD-local), t-fragments in
// A-layout registers, u round-trip through ts LDS, late scalar gathers,
// fused LN2 epilogue.
// ============================================================
__global__ __launch_bounds__(256, 3) void attn_k(
    const float* __restrict__ qbuf, const bf16_t* __restrict__ kbuf, const bf16_t* __restrict__ vbuf,
    const float* __restrict__ p, const int* __restrict__ idx,
    const float* __restrict__ Wd1, const float* __restrict__ bd1,
    const float* __restrict__ Wd2, const float* __restrict__ bd2,
    const float* __restrict__ Wa, const float* __restrict__ ba,
    const float* __restrict__ g2, const float* __restrict__ b2,
    const float* __restrict__ h, float* __restrict__ hres, bf16_t* __restrict__ h2) {
  __shared__ bf16_t ts[64 * 136];      // u matrix only
  __shared__ float hrs[4 * 128];
  __shared__ f32x4 wd1s[128];          // {Wd1[c][0..2], bd1[c]}
  __shared__ f32x4 rels4[64];          // {rx,ry,rz,0}
  __shared__ int idxs[64];
  int t = threadIdx.x;
  int lane = t & 63, w = t >> 6, quad = lane >> 4, l15 = lane & 15;
  int batch = blockIdx.x & 7, grp = blockIdx.x >> 3;
  int bn0 = batch * NN + grp * 4;
  int b = batch;
  const float* pb = p + (size_t)b * 3 * NN;
  int col0 = w * 32 + l15;
  int col1 = col0 + 16;

  bf16x8 Bd[2][4];
  #pragma unroll
  for (int t2 = 0; t2 < 2; ++t2) {
    int row = w * 32 + t2 * 16 + l15;
    #pragma unroll
    for (int s = 0; s < 4; ++s)
      Bd[t2][s] = cvt8(Wd2 + (size_t)row * CC + s * 32 + quad * 8);
  }

  if (t < 64) {
    int jj = idx[(size_t)bn0 * KNB + t];
    idxs[t] = jj;
    int npt = grp * 4 + (t >> 4);
    f32x4 rv;
    rv[0] = pb[npt]          - pb[jj];
    rv[1] = pb[NN + npt]     - pb[NN + jj];
    rv[2] = pb[2 * NN + npt] - pb[2 * NN + jj];
    rv[3] = 0.f;
    rels4[t] = rv;
  }
  if (t < 128) {
    f32x4 wv;
    wv[0] = Wd1[t * 3]; wv[1] = Wd1[t * 3 + 1]; wv[2] = Wd1[t * 3 + 2]; wv[3] = bd1[t];
    wd1s[t] = wv;
  }
  __syncthreads();

  float qv[2][4];
  #pragma unroll
  for (int mt = 0; mt < 4; ++mt) {
    qv[0][mt] = qbuf[(size_t)(bn0 + mt) * CC + col0];
    qv[1][mt] = qbuf[(size_t)(bn0 + mt) * CC + col1];
  }
  float kreg[2][4][4];
  #pragma unroll
  for (int mt = 0; mt < 4; ++mt)
    #pragma unroll
    for (int reg = 0; reg < 4; ++reg) {
      size_t base = (size_t)(b * NN + idxs[mt * 16 + quad * 4 + reg]) * CC;
      kreg[0][mt][reg] = (float)kbuf[base + col0];
      kreg[1][mt][reg] = (float)kbuf[base + col1];
    }

  f32x4 relv[4];
  #pragma unroll
  for (int mt = 0; mt < 4; ++mt) relv[mt] = rels4[mt * 16 + l15];
  f32x4 accd[2][4] = {};
  #pragma unroll
  for (int s = 0; s < 4; ++s) {
    bf16x8 af[4];
    #pragma unroll
    for (int j = 0; j < 8; ++j) {
      f32x4 wv = wd1s[s * 32 + quad * 8 + j];
      #pragma unroll
      for (int mt = 0; mt < 4; ++mt) {
        float tv = fmaf(wv[0], relv[mt][0], fmaf(wv[1], relv[mt][1], fmaf(wv[2], relv[mt][2], wv[3])));
        af[mt][j] = (__bf16)fmaxf(tv, 0.f);
      }
    }
    #pragma unroll
    for (int t2 = 0; t2 < 2; ++t2)
      #pragma unroll
      for (int mt = 0; mt < 4; ++mt)
        accd[t2][mt] = MFMA16(af[mt], Bd[t2][s], accd[t2][mt]);
  }

  {
    float b2v0 = bd2[col0], b2v1 = bd2[col1];
    #pragma unroll
    for (int mt = 0; mt < 4; ++mt)
      #pragma unroll
      for (int reg = 0; reg < 4; ++reg) {
        int row = mt * 16 + quad * 4 + reg;
        float d0 = accd[0][mt][reg] + b2v0;
        float d1 = accd[1][mt][reg] + b2v1;
        accd[0][mt][reg] = d0;
        accd[1][mt][reg] = d1;
        ts[row * 136 + col0] = (__bf16)(qv[0][mt] - kreg[0][mt][reg] + d0);
        ts[row * 136 + col1] = (__bf16)(qv[1][mt] - kreg[1][mt][reg] + d1);
      }
  }
  __syncthreads();

  float vreg[2][4][4];
  #pragma unroll
  for (int mt = 0; mt < 4; ++mt)
    #pragma unroll
    for (int reg = 0; reg < 4; ++reg) {
      size_t base = (size_t)(b * NN + idxs[mt * 16 + quad * 4 + reg]) * CC;
      vreg[0][mt][reg] = (float)vbuf[base + col0];
      vreg[1][mt][reg] = (float)vbuf[base + col1];
    }
  float hv[2][4];
  if (quad == 0) {
    #pragma unroll
    for (int mt = 0; mt < 4; ++mt) {
      hv[0][mt] = h[(size_t)(bn0 + mt) * CC + col0];
      hv[1][mt] = h[(size_t)(bn0 + mt) * CC + col1];
    }
  }
  bf16x8 Ba[2][4];
  #pragma unroll
  for (int t2 = 0; t2 < 2; ++t2) {
    int row = w * 32 + t2 * 16 + l15;
    #pragma unroll
    for (int s = 0; s < 4; ++s)
      Ba[t2][s] = cvt8(Wa + (size_t)row * CC + s * 32 + quad * 8);
  }

  f32x4 accl[2][4] = {};
  #pragma unroll
  for (int s = 0; s < 4; ++s) {
    bf16x8 af[4];
    #pragma unroll
    for (int mt = 0; mt < 4; ++mt)
      af[mt] = *(const bf16x8*)(&ts[(mt * 16 + l15) * 136 + s * 32 + quad * 8]);
    #pragma unroll
    for (int t2 = 0; t2 < 2; ++t2)
      #pragma unroll
      for (int mt = 0; mt < 4; ++mt)
        accl[t2][mt] = MFMA16(af[mt], Ba[t2][s], accl[t2][mt]);
  }

  #pragma unroll
  for (int t2 = 0; t2 < 2; ++t2) {
    int col = t2 ? col1 : col0;
    float bav = ba[col];
    #pragma unroll
    for (int mt = 0; mt < 4; ++mt) {
      float lv0 = accl[t2][mt][0] + bav, lv1 = accl[t2][mt][1] + bav;
      float lv2 = accl[t2][mt][2] + bav, lv3 = accl[t2][mt][3] + bav;
      float mx = fmaxf(fmaxf(lv0, lv1), fmaxf(lv2, lv3));
      mx = fmaxf(mx, __shfl_xor(mx, 16));
      mx = fmaxf(mx, __shfl_xor(mx, 32));
      float e0 = __expf(lv0 - mx), e1 = __expf(lv1 - mx);
      float e2 = __expf(lv2 - mx), e3 = __expf(lv3 - mx);
      float ss = e0 + e1 + e2 + e3;
      ss += __shfl_xor(ss, 16); ss += __shfl_xor(ss, 32);
      float yv = e0 * (vreg[t2][mt][0] + accd[t2][mt][0])
               + e1 * (vreg[t2][mt][1] + accd[t2][mt][1])
               + e2 * (vreg[t2][mt][2] + accd[t2][mt][2])
               + e3 * (vreg[t2][mt][3] + accd[t2][mt][3]);
      yv += __shfl_xor(yv, 16); yv += __shfl_xor(yv, 32);
      if (quad == 0) {
        float hvv = hv[t2][mt] + yv / ss;
        hres[(size_t)(bn0 + mt) * CC + col] = hvv;
        hrs[mt * 128 + col] = hvv;
      }
    }
  }
  __syncthreads();

  {
    int c0 = lane * 2;
    float v0 = hrs[w * 128 + c0], v1 = hrs[w * 128 + c0 + 1];
    float s1 = v0 + v1, s2 = v0 * v0 + v1 * v1;
    #pragma unroll
    for (int off = 1; off < 64; off <<= 1) { s1 += __shfl_xor(s1, off); s2 += __shfl_xor(s2, off); }
    float mu = s1 * (1.f / CC);
    float var = s2 * (1.f / CC) - mu * mu;
    float rs = rsqrtf(var + 1e-5f);
    bf16x2 o;
    o[0] = (__bf16)((v0 - mu) * rs * g2[c0] + b2[c0]);
    o[1] = (__bf16)((v1 - mu) * rs * g2[c0 + 1] + b2[c0 + 1]);
    *(bf16x2*)(h2 + (size_t)(bn0 + w) * CC + c0) = o;
  }
}

// ============================================================
extern "C" void kernel_launch(void* const* d_in, const int* in_sizes, int n_in,
                              void* d_out, int out_size, void* d_ws, size_t ws_size,
                              hipStream_t stream) {
  const float* x   = (const float*)d_in[0];
  const float* p   = (const float*)d_in[1];
  const float* Win = (const float*)d_in[2];
  const float* bin = (const float*)d_in[3];
  const float* Wq  = (const float*)d_in[4];
  const float* Wk  = (const float*)d_in[5];
  const float* Wv  = (const float*)d_in[6];
  const float* Wd1 = (const float*)d_in[7];
  const float* bd1 = (const float*)d_in[8];
  const float* Wd2 = (const float*)d_in[9];
  const float* bd2 = (const float*)d_in[10];
  const float* Wa  = (const float*)d_in[11];
  const float* ba  = (const float*)d_in[12];
  const float* g1  = (const float*)d_in[13];
  const float* b1  = (const float*)d_in[14];
  const float* g2  = (const float*)d_in[15];
  const float* b2  = (const float*)d_in[16];
  const float* Wf1 = (const float*)d_in[17];
  const float* bf1 = (const float*)d_in[18];
  const float* Wf2 = (const float*)d_in[19];
  const float* bf2 = (const float*)d_in[20];
  float* out = (float*)d_out;

  // workspace (R6 layout; SZ = BNT*CC = 2,097,152 floats):
  //  [0,SZ)      h fp32
  //  [SZ,2SZ)    hnb bf16 (first half) -> hres fp32
  //  [2SZ,3SZ)   q fp32        } -> g bf16 overlays [2SZ,4SZ) for FFN
  //  [3SZ,3.5SZ) kb bf16       }
  //  [3.5SZ,4SZ) vb bf16       }
  //  [4SZ,4.5SZ) h2 bf16
  //  [4.5SZ,..)  idx int[BNT*16]
  const size_t SZ = (size_t)BNT * CC;
  float* wsf = (float*)d_ws;
  float*  h    = wsf;
  bf16_t* hnb  = (bf16_t*)(wsf + SZ);
  float*  hres = wsf + SZ;
  float*  q    = wsf + 2 * SZ;
  bf16_t* kb   = (bf16_t*)(wsf + 3 * SZ);
  bf16_t* vb   = kb + SZ;
  bf16_t* g    = (bf16_t*)(wsf + 2 * SZ);
  bf16_t* h2   = (bf16_t*)(wsf + 4 * SZ);
  int*    idxw = (int*)(wsf + 4 * SZ + SZ / 2);

  inproj_ln_k<<<BNT / 64, 256, 0, stream>>>(x, Win, bin, g1, b1, h, hnb);
  knn_qkv_k<<<4096 + 1536, 256, 0, stream>>>(p, idxw, hnb, Wq, Wk, Wv, q, kb, vb);
  attn_k<<<BNT / 4, 256, 0, stream>>>(q, kb, vb, p, idxw, Wd1, bd1, Wd2, bd2, Wa, ba,
                                      g2, b2, h, hres, h2);
  gemm_k<1><<<dim3(BNT / 64, 8), 256, 0, stream>>>(h2, Wf1, bf1, nullptr, g, nullptr, 4 * CC, CC);
  gemm_k<2><<<dim3(BNT / 64, 2), 256, 0, stream>>>(g, Wf2, bf2, out, nullptr, hres, CC, 4 * CC);
}

// Round 11
// 266.019 us; speedup vs baseline: 1.6283x; 1.1094x over previous
//
#include <hip/hip_runtime.h>

typedef __bf16 bf16_t;
typedef __bf16 bf16x8 __attribute__((ext_vector_type(8)));
typedef __bf16 bf16x2 __attribute__((ext_vector_type(2)));
typedef float  f32x4  __attribute__((ext_vector_type(4)));

#define MFMA16(a,b,c) __builtin_amdgcn_mfma_f32_16x16x32_bf16((a),(b),(c),0,0,0)

// ---- constants (problem is fixed-shape) ----
#define BB 8
#define NN 2048
#define CC 128
#define CIN 64
#define KNB 16            // neighbors
#define BNT (BB*NN)       // 16384 points

// XCD affinity: batch a block touches == blockIdx%8 == its XCD (R6-verified:
// cut attn FETCH 38->13.5 MB).
static __device__ __forceinline__ int remap256(int x) { return ((x & 7) << 5) | (x >> 3); }

static __device__ __forceinline__ bf16x8 cvt8(const float* src) {
  f32x4 a0 = *(const f32x4*)src;
  f32x4 a1 = *(const f32x4*)(src + 4);
  bf16x8 fr;
  fr[0] = (__bf16)a0[0]; fr[1] = (__bf16)a0[1]; fr[2] = (__bf16)a0[2]; fr[3] = (__bf16)a0[3];
  fr[4] = (__bf16)a1[0]; fr[5] = (__bf16)a1[1]; fr[6] = (__bf16)a1[2]; fr[7] = (__bf16)a1[3];
  return fr;
}

// ============================================================
// Kernel 0: bf16 weight conversion (plain casts, RNE — bit-identical to
// the in-kernel cvt8 it replaces). y: 0 Wq,1 Wk,2 Wv,3 Wd2,4 Wa,5 Wf1,6 Wf2.
// grid (8,7), block 256.
// ============================================================
__global__ __launch_bounds__(256) void compw_k(
    const float* __restrict__ Wq, const float* __restrict__ Wk, const float* __restrict__ Wv,
    const float* __restrict__ Wd2, const float* __restrict__ Wa,
    const float* __restrict__ Wf1, const float* __restrict__ Wf2,
    bf16_t* __restrict__ Wqb, bf16_t* __restrict__ Wkb, bf16_t* __restrict__ Wvb,
    bf16_t* __restrict__ Wd2b, bf16_t* __restrict__ Wab,
    bf16_t* __restrict__ Wf1b, bf16_t* __restrict__ Wf2b) {
  int mat = blockIdx.y;
  int nel = (mat >= 5) ? 65536 : 16384;
  const float* S = mat == 0 ? Wq : mat == 1 ? Wk : mat == 2 ? Wv : mat == 3 ? Wd2
                 : mat == 4 ? Wa : mat == 5 ? Wf1 : Wf2;
  bf16_t* D = mat == 0 ? Wqb : mat == 1 ? Wkb : mat == 2 ? Wvb : mat == 3 ? Wd2b
            : mat == 4 ? Wab : mat == 5 ? Wf1b : Wf2b;
  for (int i = blockIdx.x * 256 + threadIdx.x; i * 8 < nel; i += 2048)
    *(bf16x8*)(D + i * 8) = cvt8(S + i * 8);
}

// ============================================================
// Kernel 1: in_proj + LN1, MFMA-based (R6 verbatim).
// ============================================================
__global__ __launch_bounds__(256) void inproj_ln_k(
    const float* __restrict__ x, const float* __restrict__ Win, const float* __restrict__ bin,
    const float* __restrict__ g1, const float* __restrict__ b1,
    float* __restrict__ h, bf16_t* __restrict__ hnb) {
  __shared__ bf16_t As[64 * 72];
  __shared__ bf16_t Bs[128 * 72];
  __shared__ float hs[64 * 132];
  int t = threadIdx.x;
  int lane = t & 63, w = t >> 6, quad = lane >> 4, l15 = lane & 15;
  int mBase = remap256(blockIdx.x) * 64;
  int b = mBase >> 11, n0 = mBase & (NN - 1);
  const float* xb = x + (size_t)b * CIN * NN;
  {
    int k = t >> 2, part = t & 3;
    #pragma unroll
    for (int i = 0; i < 4; ++i) {
      f32x4 v = *(const f32x4*)(xb + (size_t)k * NN + n0 + part * 16 + i * 4);
      #pragma unroll
      for (int j2 = 0; j2 < 4; ++j2) As[(part * 16 + i * 4 + j2) * 72 + k] = (__bf16)v[j2];
    }
  }
  {
    int row = t >> 1, seg = (t & 1) * 32;
    #pragma unroll
    for (int i = 0; i < 4; ++i)
      *(bf16x8*)(&Bs[row * 72 + seg + i * 8]) = cvt8(Win + (size_t)row * CIN + seg + i * 8);
  }
  __syncthreads();
  f32x4 acc[2][4] = {};
  #pragma unroll
  for (int s = 0; s < 2; ++s) {
    bf16x8 af[4];
    #pragma unroll
    for (int mt = 0; mt < 4; ++mt)
      af[mt] = *(const bf16x8*)(&As[(mt * 16 + l15) * 72 + s * 32 + quad * 8]);
    #pragma unroll
    for (int t2 = 0; t2 < 2; ++t2) {
      bf16x8 bfr = *(const bf16x8*)(&Bs[((w * 2 + t2) * 16 + l15) * 72 + s * 32 + quad * 8]);
      #pragma unroll
      for (int mt = 0; mt < 4; ++mt) acc[t2][mt] = MFMA16(af[mt], bfr, acc[t2][mt]);
    }
  }
  #pragma unroll
  for (int t2 = 0; t2 < 2; ++t2) {
    int col = (w * 2 + t2) * 16 + l15;
    float bv = bin[col];
    #pragma unroll
    for (int mt = 0; mt < 4; ++mt)
      #pragma unroll
      for (int reg = 0; reg < 4; ++reg)
        hs[(mt * 16 + quad * 4 + reg) * 132 + col] = acc[t2][mt][reg] + bv;
  }
  __syncthreads();
  {
    int row = t >> 2, c0 = (t & 3) * 32;
    float v[32];
    #pragma unroll
    for (int i = 0; i < 8; ++i) *(f32x4*)(v + i * 4) = *(const f32x4*)(&hs[row * 132 + c0 + i * 4]);
    float s1 = 0.f, s2 = 0.f;
    #pragma unroll
    for (int i = 0; i < 32; ++i) { s1 += v[i]; s2 += v[i] * v[i]; }
    s1 += __shfl_xor(s1, 1); s1 += __shfl_xor(s1, 2);
    s2 += __shfl_xor(s2, 1); s2 += __shfl_xor(s2, 2);
    float mu = s1 * (1.f / CC);
    float var = s2 * (1.f / CC) - mu * mu;
    float rs = rsqrtf(var + 1e-5f);
    float* hrow = h + (size_t)(mBase + row) * CC + c0;
    #pragma unroll
    for (int i = 0; i < 8; ++i) *(f32x4*)(hrow + i * 4) = *(const f32x4*)(v + i * 4);
    bf16_t* hnrow = hnb + (size_t)(mBase + row) * CC + c0;
    #pragma unroll
    for (int i = 0; i < 4; ++i) {
      f32x4 g4a = ((const f32x4*)g1)[(c0 >> 2) + i * 2],     g4b = ((const f32x4*)g1)[(c0 >> 2) + i * 2 + 1];
      f32x4 b4a = ((const f32x4*)b1)[(c0 >> 2) + i * 2],     b4b = ((const f32x4*)b1)[(c0 >> 2) + i * 2 + 1];
      bf16x8 o;
      #pragma unroll
      for (int j = 0; j < 4; ++j) o[j]     = (__bf16)((v[i * 8 + j]     - mu) * rs * g4a[j] + b4a[j]);
      #pragma unroll
      for (int j = 0; j < 4; ++j) o[4 + j] = (__bf16)((v[i * 8 + 4 + j] - mu) * rs * g4b[j] + b4b[j]);
      *(bf16x8*)(hnrow + i * 8) = o;
    }
  }
}

// ============================================================
// KNN body (R6 verbatim, LDS passed in).
// ============================================================
static __device__ __forceinline__ void cas(double& a, double& b) {
  double lo = fmin(a, b), hi = fmax(a, b); a = lo; b = hi;
}
#define S8(K,o) \
  cas(K[o+0],K[o+1]); cas(K[o+2],K[o+3]); cas(K[o+4],K[o+5]); cas(K[o+6],K[o+7]); \
  cas(K[o+0],K[o+2]); cas(K[o+1],K[o+3]); cas(K[o+4],K[o+6]); cas(K[o+5],K[o+7]); \
  cas(K[o+1],K[o+2]); cas(K[o+5],K[o+6]); \
  cas(K[o+0],K[o+4]); cas(K[o+1],K[o+5]); cas(K[o+2],K[o+6]); cas(K[o+3],K[o+7]); \
  cas(K[o+2],K[o+4]); cas(K[o+3],K[o+5]); \
  cas(K[o+1],K[o+2]); cas(K[o+3],K[o+4]); cas(K[o+5],K[o+6]);
#define M8(K,a,b) \
  K[a+0]=fmin(K[a+0],K[b+7]); K[a+1]=fmin(K[a+1],K[b+6]); K[a+2]=fmin(K[a+2],K[b+5]); K[a+3]=fmin(K[a+3],K[b+4]); \
  K[a+4]=fmin(K[a+4],K[b+3]); K[a+5]=fmin(K[a+5],K[b+2]); K[a+6]=fmin(K[a+6],K[b+1]); K[a+7]=fmin(K[a+7],K[b+0]); \
  cas(K[a+0],K[a+4]); cas(K[a+1],K[a+5]); cas(K[a+2],K[a+6]); cas(K[a+3],K[a+7]); \
  cas(K[a+0],K[a+2]); cas(K[a+1],K[a+3]); cas(K[a+4],K[a+6]); cas(K[a+5],K[a+7]); \
  cas(K[a+0],K[a+1]); cas(K[a+2],K[a+3]); cas(K[a+4],K[a+5]); cas(K[a+6],K[a+7]);

static __device__ void knn_impl(float* sp, const float* __restrict__ p,
                                int* __restrict__ idxo, int bid) {
  float* px = sp; float* py = sp + NN; float* pz = sp + 2 * NN;
  int t = threadIdx.x;
  int b = bid >> 9;
  int g = bid & 511;
  const float* pb = p + (size_t)b * 3 * NN;
  for (int i = t; i < NN; i += 256) { px[i] = pb[i]; py[i] = pb[NN + i]; pz[i] = pb[2 * NN + i]; }
  __syncthreads();
  int w = t >> 6, lane = t & 63;
  int n = g * 4 + w;
  float pnx = px[n], pny = py[n], pnz = pz[n];
  double key[32];
  #pragma unroll
  for (int s = 0; s < 32; ++s) {
    int m = s * 64 + lane;
    float dx = pnx - px[m], dy = pny - py[m], dz = pnz - pz[m];
    float dist = dx * dx + dy * dy + dz * dz;
    unsigned db = (m == n) ? 0x7F800000u : __float_as_uint(dist);
    key[s] = __hiloint2double((int)db, m);
  }
  S8(key, 0); S8(key, 8); S8(key, 16); S8(key, 24);
  M8(key, 0, 8); M8(key, 16, 24); M8(key, 0, 16);
  const double DINF = __hiloint2double(0x7F900000, 0);
  int* myout = idxo + ((size_t)b * NN + n) * KNB;
  #pragma unroll 1
  for (int r = 0; r < 16; ++r) {
    double gm = key[0];
    #pragma unroll
    for (int off = 1; off < 64; off <<= 1) {
      double o = __shfl_xor(gm, off);
      gm = fmin(gm, o);
    }
    if (lane == 0) myout[r] = __double2loint(gm);
    bool win = (key[0] == gm);
    key[0] = win ? key[1] : key[0];
    key[1] = win ? key[2] : key[1];
    key[2] = win ? key[3] : key[2];
    key[3] = win ? key[4] : key[3];
    key[4] = win ? key[5] : key[4];
    key[5] = win ? key[6] : key[5];
    key[6] = win ? key[7] : key[6];
    key[7] = win ? DINF   : key[7];
  }
}

// ============================================================
// 64x64 GEMM body, BK=32 (R6-proven occupancy: 10.6 KB LDS), A and W
// both bf16 (W pre-converted — staging is a straight copy).
// EPI: 0 fp32, 1 relu->bf16, 2 +resid transposed fp32 [B,C,N], 3 bf16.
// ============================================================
template<int EPI>
static __device__ void gemm_body(bf16_t* As, bf16_t* Bs,
    const bf16_t* __restrict__ Ab, const bf16_t* __restrict__ Wb, const float* __restrict__ bias,
    float* __restrict__ outF, bf16_t* __restrict__ outB, const float* __restrict__ resid,
    int mBase, int nBase, int Ncol, int Kdim) {
  int t = threadIdx.x;
  int lane = t & 63, w = t >> 6, quad = lane >> 4, l15 = lane & 15;
  int r = t >> 2, seg = (t & 3) * 8;
  f32x4 acc[4] = {{0,0,0,0},{0,0,0,0},{0,0,0,0},{0,0,0,0}};
  for (int k0 = 0; k0 < Kdim; k0 += 32) {
    __syncthreads();
    *(bf16x8*)(&As[r * 40 + seg]) = *(const bf16x8*)(Ab + (size_t)(mBase + r) * Kdim + k0 + seg);
    *(bf16x8*)(&Bs[r * 40 + seg]) = *(const bf16x8*)(Wb + (size_t)(nBase + r) * Kdim + k0 + seg);
    __syncthreads();
    bf16x8 bfr = *(const bf16x8*)(&Bs[(w * 16 + l15) * 40 + quad * 8]);
    #pragma unroll
    for (int mt = 0; mt < 4; ++mt) {
      bf16x8 afr = *(const bf16x8*)(&As[(mt * 16 + l15) * 40 + quad * 8]);
      acc[mt] = MFMA16(afr, bfr, acc[mt]);
    }
  }
  int n = nBase + w * 16 + l15;
  float bv = bias ? bias[n] : 0.f;
  #pragma unroll
  for (int mt = 0; mt < 4; ++mt) {
    #pragma unroll
    for (int reg = 0; reg < 4; ++reg) {
      int m = mBase + mt * 16 + quad * 4 + reg;
      float val = acc[mt][reg] + bv;
      if (EPI == 0) {
        outF[(size_t)m * Ncol + n] = val;
      } else if (EPI == 1) {
        outB[(size_t)m * Ncol + n] = (__bf16)fmaxf(val, 0.f);
      } else if (EPI == 3) {
        outB[(size_t)m * Ncol + n] = (__bf16)val;
      } else {
        val += resid[(size_t)m * CC + n];
        int bo = m >> 11, np = m & (NN - 1);
        outF[((size_t)bo * CC + n) * NN + np] = val;
      }
    }
  }
}

template<int EPI>
__global__ __launch_bounds__(256) void gemm_k(
    const bf16_t* __restrict__ Ab, const bf16_t* __restrict__ Wb, const float* __restrict__ bias,
    float* __restrict__ outF, bf16_t* __restrict__ outB, const float* __restrict__ resid,
    int Ncol, int Kdim) {
  __shared__ bf16_t As[64 * 40];
  __shared__ bf16_t Bs[64 * 40];
  gemm_body<EPI>(As, Bs, Ab, Wb, bias, outF, outB, resid,
                 remap256(blockIdx.x) * 64, blockIdx.y * 64, Ncol, Kdim);
}

// ============================================================
// Fused knn + qkv dispatch. Blocks [0,4096): knn (pure VALU, 24.6 KB LDS).
// Blocks [4096,5632): qkv GEMM (MFMA+mem, 10.6 KB of the union).
// Union LDS 24.6 KB -> 6 blocks/CU (R10's 34.8 KB was the regression).
// ============================================================
__global__ __launch_bounds__(256) void knn_qkv_k(
    const float* __restrict__ p, int* __restrict__ idxo,
    const bf16_t* __restrict__ hnb,
    const bf16_t* __restrict__ Wqb, const bf16_t* __restrict__ Wkb, const bf16_t* __restrict__ Wvb,
    float* __restrict__ q, bf16_t* __restrict__ kb, bf16_t* __restrict__ vb) {
  __shared__ __align__(16) char smem[3 * NN * 4];   // 24576 B
  if (blockIdx.x < 4096) {
    knn_impl((float*)smem, p, idxo, blockIdx.x);
  } else {
    bf16_t* As = (bf16_t*)smem;
    bf16_t* Bs = As + 64 * 40;
    int bx = blockIdx.x - 4096;
    int yy = bx >> 8, xx = bx & 255;
    int sel = yy >> 1;
    int mB = remap256(xx) * 64, nB = (yy & 1) * 64;
    if (sel == 0)      gemm_body<0>(As, Bs, hnb, Wqb, nullptr, q,  nullptr, nullptr, mB, nB, CC, CC);
    else if (sel == 1) gemm_body<3>(As, Bs, hnb, Wkb, nullptr, nullptr, kb, nullptr, mB, nB, CC, CC);
    else               gemm_body<3>(As, Bs, hnb, Wvb, nullptr, nullptr, vb, nullptr, mB, nB, CC, CC);
  }
}

// ============================================================
// Kernel 5: fused neighbor attention (R10/R6 math verbatim; only change:
// Bd/Ba fragments load pre-converted bf16 weights directly — bit-identical
// values, ~300 fewer VALU + 64 fewer f32x4 loads per block).
// ============================================================
__global__ __launch_bounds__(256, 3) void attn_k(
    const float* __restrict__ qbuf, const bf16_t* __restrict__ kbuf, const bf16_t* __restrict__ vbuf,
    const float* __restrict__ p, const int* __restrict__ idx,
    const float* __restrict__ Wd1, const float* __restrict__ bd1,
    const bf16_t* __restrict__ Wd2b, const float* __restrict__ bd2,
    const bf16_t* __restrict__ Wab, const float* __restrict__ ba,
    const float* __restrict__ g2, const float* __restrict__ b2,
    const float* __restrict__ h, float* __restrict__ hres, bf16_t* __restrict__ h2) {
  __shared__ bf16_t ts[64 * 136];      // u matrix only
  __shared__ float hrs[4 * 128];
  __shared__ f32x4 wd1s[128];          // {Wd1[c][0..2], bd1[c]}
  __shared__ f32x4 rels4[64];          // {rx,ry,rz,0}
  __shared__ int idxs[64];
  int t = threadIdx.x;
  int lane = t & 63, w = t >> 6, quad = lane >> 4, l15 = lane & 15;
  int batch = blockIdx.x & 7, grp = blockIdx.x >> 3;
  int bn0 = batch * NN + grp * 4;
  int b = batch;
  const float* pb = p + (size_t)b * 3 * NN;
  int col0 = w * 32 + l15;
  int col1 = col0 + 16;

  bf16x8 Bd[2][4];
  #pragma unroll
  for (int t2 = 0; t2 < 2; ++t2) {
    int row = w * 32 + t2 * 16 + l15;
    #pragma unroll
    for (int s = 0; s < 4; ++s)
      Bd[t2][s] = *(const bf16x8*)(Wd2b + (size_t)row * CC + s * 32 + quad * 8);
  }

  if (t < 64) {
    int jj = idx[(size_t)bn0 * KNB + t];
    idxs[t] = jj;
    int npt = grp * 4 + (t >> 4);
    f32x4 rv;
    rv[0] = pb[npt]          - pb[jj];
    rv[1] = pb[NN + npt]     - pb[NN + jj];
    rv[2] = pb[2 * NN + npt] - pb[2 * NN + jj];
    rv[3] = 0.f;
    rels4[t] = rv;
  }
  if (t < 128) {
    f32x4 wv;
    wv[0] = Wd1[t * 3]; wv[1] = Wd1[t * 3 + 1]; wv[2] = Wd1[t * 3 + 2]; wv[3] = bd1[t];
    wd1s[t] = wv;
  }
  __syncthreads();

  float qv[2][4];
  #pragma unroll
  for (int mt = 0; mt < 4; ++mt) {
    qv[0][mt] = qbuf[(size_t)(bn0 + mt) * CC + col0];
    qv[1][mt] = qbuf[(size_t)(bn0 + mt) * CC + col1];
  }
  float kreg[2][4][4];
  #pragma unroll
  for (int mt = 0; mt < 4; ++mt)
    #pragma unroll
    for (int reg = 0; reg < 4; ++reg) {
      size_t base = (size_t)(b * NN + idxs[mt * 16 + quad * 4 + reg]) * CC;
      kreg[0][mt][reg] = (float)kbuf[base + col0];
      kreg[1][mt][reg] = (float)kbuf[base + col1];
    }

  f32x4 relv[4];
  #pragma unroll
  for (int mt = 0; mt < 4; ++mt) relv[mt] = rels4[mt * 16 + l15];
  f32x4 accd[2][4] = {};
  #pragma unroll
  for (int s = 0; s < 4; ++s) {
    bf16x8 af[4];
    #pragma unroll
    for (int j = 0; j < 8; ++j) {
      f32x4 wv = wd1s[s * 32 + quad * 8 + j];
      #pragma unroll
      for (int mt = 0; mt < 4; ++mt) {
        float tv = fmaf(wv[0], relv[mt][0], fmaf(wv[1], relv[mt][1], fmaf(wv[2], relv[mt][2], wv[3])));
        af[mt][j] = (__bf16)fmaxf(tv, 0.f);
      }
    }
    #pragma unroll
    for (int t2 = 0; t2 < 2; ++t2)
      #pragma unroll
      for (int mt = 0; mt < 4; ++mt)
        accd[t2][mt] = MFMA16(af[mt], Bd[t2][s], accd[t2][mt]);
  }

  {
    float b2v0 = bd2[col0], b2v1 = bd2[col1];
    #pragma unroll
    for (int mt = 0; mt < 4; ++mt)
      #pragma unroll
      for (int reg = 0; reg < 4; ++reg) {
        int row = mt * 16 + quad * 4 + reg;
        float d0 = accd[0][mt][reg] + b2v0;
        float d1 = accd[1][mt][reg] + b2v1;
        accd[0][mt][reg] = d0;
        accd[1][mt][reg] = d1;
        ts[row * 136 + col0] = (__bf16)(qv[0][mt] - kreg[0][mt][reg] + d0);
        ts[row * 136 + col1] = (__bf16)(qv[1][mt] - kreg[1][mt][reg] + d1);
      }
  }
  __syncthreads();

  float vreg[2][4][4];
  #pragma unroll
  for (int mt = 0; mt < 4; ++mt)
    #pragma unroll
    for (int reg = 0; reg < 4; ++reg) {
      size_t base = (size_t)(b * NN + idxs[mt * 16 + quad * 4 + reg]) * CC;
      vreg[0][mt][reg] = (float)vbuf[base + col0];
      vreg[1][mt][reg] = (float)vbuf[base + col1];
    }
  float hv[2][4];
  if (quad == 0) {
    #pragma unroll
    for (int mt = 0; mt < 4; ++mt) {
      hv[0][mt] = h[(size_t)(bn0 + mt) * CC + col0];
      hv[1][mt] = h[(size_t)(bn0 + mt) * CC + col1];
    }
  }
  bf16x8 Ba[2][4];
  #pragma unroll
  for (int t2 = 0; t2 < 2; ++t2) {
    int row = w * 32 + t2 * 16 + l15;
    #pragma unroll
    for (int s = 0; s < 4; ++s)
      Ba[t2][s] = *(const bf16x8*)(Wab + (size_t)row * CC + s * 32 + quad * 8);
  }

  f32x4 accl[2][4] = {};
  #pragma unroll
  for (int s = 0; s < 4; ++s) {
    bf16x8 af[4];
    #pragma unroll
    for (int mt = 0; mt < 4; ++mt)
      af[mt] = *(const bf16x8*)(&ts[(mt * 16 + l15) * 136 + s * 32 + quad * 8]);
    #pragma unroll
    for (int t2 = 0; t2 < 2; ++t2)
      #pragma unroll
      for (int mt = 0; mt < 4; ++mt)
        accl[t2][mt] = MFMA16(af[mt], Ba[t2][s], accl[t2][mt]);
  }

  #pragma unroll
  for (int t2 = 0; t2 < 2; ++t2) {
    int col = t2 ? col1 : col0;
    float bav = ba[col];
    #pragma unroll
    for (int mt = 0; mt < 4; ++mt) {
      float lv0 = accl[t2][mt][0] + bav, lv1 = accl[t2][mt][1] + bav;
      float lv2 = accl[t2][mt][2] + bav, lv3 = accl[t2][mt][3] + bav;
      float mx = fmaxf(fmaxf(lv0, lv1), fmaxf(lv2, lv3));
      mx = fmaxf(mx, __shfl_xor(mx, 16));
      mx = fmaxf(mx, __shfl_xor(mx, 32));
      float e0 = __expf(lv0 - mx), e1 = __expf(lv1 - mx);
      float e2 = __expf(lv2 - mx), e3 = __expf(lv3 - mx);
      float ss = e0 + e1 + e2 + e3;
      ss += __shfl_xor(ss, 16); ss += __shfl_xor(ss, 32);
      float yv = e0 * (vreg[t2][mt][0] + accd[t2][mt][0])
               + e1 * (vreg[t2][mt][1] + accd[t2][mt][1])
               + e2 * (vreg[t2][mt][2] + accd[t2][mt][2])
               + e3 * (vreg[t2][mt][3] + accd[t2][mt][3]);
      yv += __shfl_xor(yv, 16); yv += __shfl_xor(yv, 32);
      if (quad == 0) {
        float hvv = hv[t2][mt] + yv / ss;
        hres[(size_t)(bn0 + mt) * CC + col] = hvv;
        hrs[mt * 128 + col] = hvv;
      }
    }
  }
  __syncthreads();

  {
    int c0 = lane * 2;
    float v0 = hrs[w * 128 + c0], v1 = hrs[w * 128 + c0 + 1];
    float s1 = v0 + v1, s2 = v0 * v0 + v1 * v1;
    #pragma unroll
    for (int off = 1; off < 64; off <<= 1) { s1 += __shfl_xor(s1, off); s2 += __shfl_xor(s2, off); }
    float mu = s1 * (1.f / CC);
    float var = s2 * (1.f / CC) - mu * mu;
    float rs = rsqrtf(var + 1e-5f);
    bf16x2 o;
    o[0] = (__bf16)((v0 - mu) * rs * g2[c0] + b2[c0]);
    o[1] = (__bf16)((v1 - mu) * rs * g2[c0 + 1] + b2[c0 + 1]);
    *(bf16x2*)(h2 + (size_t)(bn0 + w) * CC + c0) = o;
  }
}

// ============================================================
extern "C" void kernel_launch(void* const* d_in, const int* in_sizes, int n_in,
                              void* d_out, int out_size, void* d_ws, size_t ws_size,
                              hipStream_t stream) {
  const float* x   = (const float*)d_in[0];
  const float* p   = (const float*)d_in[1];
  const float* Win = (const float*)d_in[2];
  const float* bin = (const float*)d_in[3];
  const float* Wq  = (const float*)d_in[4];
  const float* Wk  = (const float*)d_in[5];
  const float* Wv  = (const float*)d_in[6];
  const float* Wd1 = (const float*)d_in[7];
  const float* bd1 = (const float*)d_in[8];
  const float* Wd2 = (const float*)d_in[9];
  const float* bd2 = (const float*)d_in[10];
  const float* Wa  = (const float*)d_in[11];
  const float* ba  = (const float*)d_in[12];
  const float* g1  = (const float*)d_in[13];
  const float* b1  = (const float*)d_in[14];
  const float* g2  = (const float*)d_in[15];
  const float* b2  = (const float*)d_in[16];
  const float* Wf1 = (const float*)d_in[17];
  const float* bf1 = (const float*)d_in[18];
  const float* Wf2 = (const float*)d_in[19];
  const float* bf2 = (const float*)d_in[20];
  float* out = (float*)d_out;

  // workspace (SZ = BNT*CC = 2,097,152 floats):
  //  [0,SZ)      h fp32
  //  [SZ,2SZ)    hnb bf16 (first half) -> hres fp32
  //  [2SZ,3SZ)   q fp32        } -> g bf16 overlays [2SZ,4SZ) for FFN
  //  [3SZ,3.5SZ) kb bf16       }
  //  [3.5SZ,4SZ) vb bf16       }
  //  [4SZ,4.5SZ) h2 bf16
  //  [4.5SZ,..)  idx int[BNT*16] | bf16 weights (0.43 MB)
  const size_t SZ = (size_t)BNT * CC;
  float* wsf = (float*)d_ws;
  float*  h    = wsf;
  bf16_t* hnb  = (bf16_t*)(wsf + SZ);
  float*  hres = wsf + SZ;
  float*  q    = wsf + 2 * SZ;
  bf16_t* kb   = (bf16_t*)(wsf + 3 * SZ);
  bf16_t* vb   = kb + SZ;
  bf16_t* g    = (bf16_t*)(wsf + 2 * SZ);
  bf16_t* h2   = (bf16_t*)(wsf + 4 * SZ);
  int*    idxw = (int*)(wsf + 4 * SZ + SZ / 2);
  bf16_t* Wqb  = (bf16_t*)(idxw + (size_t)BNT * KNB);
  bf16_t* Wkb  = Wqb  + 16384;
  bf16_t* Wvb  = Wkb  + 16384;
  bf16_t* Wd2b = Wvb  + 16384;
  bf16_t* Wab  = Wd2b + 16384;
  bf16_t* Wf1b = Wab  + 16384;
  bf16_t* Wf2b = Wf1b + 65536;

  compw_k<<<dim3(8, 7), 256, 0, stream>>>(Wq, Wk, Wv, Wd2, Wa, Wf1, Wf2,
                                          Wqb, Wkb, Wvb, Wd2b, Wab, Wf1b, Wf2b);
  inproj_ln_k<<<BNT / 64, 256, 0, stream>>>(x, Win, bin, g1, b1, h, hnb);
  knn_qkv_k<<<4096 + 1536, 256, 0, stream>>>(p, idxw, hnb, Wqb, Wkb, Wvb, q, kb, vb);
  attn_k<<<BNT / 4, 256, 0, stream>>>(q, kb, vb, p, idxw, Wd1, bd1, Wd2b, bd2, Wab, ba,
                                      g2, b2, h, hres, h2);
  gemm_k<1><<<dim3(BNT / 64, 8), 256, 0, stream>>>(h2, Wf1b, bf1, nullptr, g, nullptr, 4 * CC, CC);
  gemm_k<2><<<dim3(BNT / 64, 2), 256, 0, stream>>>(g, Wf2b, bf2, out, nullptr, hres, CC, 4 * CC);
}